// Round 4
// baseline (4071.043 us; speedup 1.0000x reference)
//
#include <hip/hip_runtime.h>
#include <stdint.h>

#define N_NODES 100000
#define N_EDGES 3200000
#define N_BKT 782          // ceil(100000/128)
#define BKT_SHIFT 7
#define BKT_SIZE 128
#define CHUNK 4096

typedef unsigned int u32;
typedef unsigned short u16;
typedef short short8 __attribute__((ext_vector_type(8)));
typedef float f32x4 __attribute__((ext_vector_type(4)));

__device__ __forceinline__ u16 f32_bf16(float f) {
  u32 u = __float_as_uint(f);
  u += 0x7fffu + ((u >> 16) & 1u);   // RNE
  return (u16)(u >> 16);
}
__device__ __forceinline__ float bf_lo(u32 p) { return __uint_as_float(p << 16); }
__device__ __forceinline__ float bf_hi(u32 p) { return __uint_as_float(p & 0xffff0000u); }

// ---------------- bucket histogram ----------------

__global__ __launch_bounds__(1024) void k_zero2(int* ghist) {
  ghist[threadIdx.x] = 0;
}

__global__ __launch_bounds__(256) void k_hist(const int* __restrict__ eid,
                                              int* __restrict__ ghist) {
  __shared__ int hh[1024];
  int t = threadIdx.x;
  for (int b = t; b < 1024; b += 256) hh[b] = 0;
  __syncthreads();
  int base = blockIdx.x * CHUNK;
#pragma unroll
  for (int k = 0; k < 16; ++k) {
    int e = base + t + 256 * k;
    if (e < N_EDGES) atomicAdd(&hh[eid[e] >> BKT_SHIFT], 1);
  }
  __syncthreads();
  for (int b = t; b < 1024; b += 256) {
    int c = hh[b];
    if (c) atomicAdd(&ghist[b], c);
  }
}

// single-block scan of 782 bucket counts -> bases + global cursors
__global__ __launch_bounds__(1024) void k_base(const int* __restrict__ ghist,
                                               int* __restrict__ bb,
                                               int* __restrict__ gcur) {
  __shared__ int sm[1024];
  int t = threadIdx.x;
  int v = (t < N_BKT) ? ghist[t] : 0;
  sm[t] = v;
  __syncthreads();
  for (int off = 1; off < 1024; off <<= 1) {
    int add = (t >= off) ? sm[t - off] : 0;
    __syncthreads();
    sm[t] += add;
    __syncthreads();
  }
  int ex = sm[t] - v;
  if (t < N_BKT) { bb[t] = ex; gcur[t] = ex; }
  if (t == 0) bb[N_BKT] = N_EDGES;
}

// ---------------- binning: block-local counting sort + coalesced flush -----
// entry pack: x = src | (dst&127)<<20 ; y = weight fp32

__global__ __launch_bounds__(256) void k_bin(const int* __restrict__ eis,
                                             const int* __restrict__ eid,
                                             const float* __restrict__ ew,
                                             int* __restrict__ gcur,
                                             uint2* __restrict__ binned) {
  __shared__ int cnt[1024];
  __shared__ int lstart[1024];
  __shared__ int delta[1024];
  __shared__ int lcur[1024];
  __shared__ int part[256];
  __shared__ uint2 stage[CHUNK];
  __shared__ u16 sbkt[CHUNK];
  int t = threadIdx.x;
  for (int b = t; b < 1024; b += 256) cnt[b] = 0;
  __syncthreads();
  int base = blockIdx.x * CHUNK;
  int cc = N_EDGES - base; if (cc > CHUNK) cc = CHUNK;
#pragma unroll
  for (int k = 0; k < 16; ++k) {
    int e = base + t + 256 * k;
    if (e < N_EDGES) atomicAdd(&cnt[eid[e] >> BKT_SHIFT], 1);
  }
  __syncthreads();
  // scan of 1024 bucket counts (4 per thread)
  int b4 = t * 4;
  int c0 = cnt[b4], c1 = cnt[b4 + 1], c2 = cnt[b4 + 2], c3 = cnt[b4 + 3];
  int bs = c0 + c1 + c2 + c3;
  part[t] = bs;
  __syncthreads();
  for (int off = 1; off < 256; off <<= 1) {
    int add = (t >= off) ? part[t - off] : 0;
    __syncthreads();
    part[t] += add;
    __syncthreads();
  }
  int ex = part[t] - bs;
  lstart[b4] = ex;                 lcur[b4] = ex;
  lstart[b4 + 1] = ex + c0;        lcur[b4 + 1] = ex + c0;
  lstart[b4 + 2] = ex + c0 + c1;   lcur[b4 + 2] = ex + c0 + c1;
  lstart[b4 + 3] = ex + c0 + c1 + c2; lcur[b4 + 3] = ex + c0 + c1 + c2;
  __syncthreads();
  // reserve global runs per bucket
  for (int b = t; b < 1024; b += 256) {
    int c = cnt[b];
    if (c) {
      int g = atomicAdd(&gcur[b], c);
      delta[b] = g - lstart[b];
    }
  }
  // stage into LDS, bucket-grouped
#pragma unroll
  for (int k = 0; k < 16; ++k) {
    int e = base + t + 256 * k;
    if (e < N_EDGES) {
      int dst = eid[e];
      int bkt = dst >> BKT_SHIFT;
      int pos = atomicAdd(&lcur[bkt], 1);
      stage[pos] = make_uint2((u32)eis[e] | ((u32)(dst & (BKT_SIZE - 1)) << 20),
                              __float_as_uint(ew[e]));
      sbkt[pos] = (u16)bkt;
    }
  }
  __syncthreads();
  // coalesced flush
  for (int idx = t; idx < cc; idx += 256) {
    int bkt = sbkt[idx];
    binned[delta[bkt] + idx] = stage[idx];
  }
}

// ---------------- W1 transpose+convert: W1t[c][k] bf16 ----------------

__global__ void k_w1t(const float* __restrict__ W1, u16* __restrict__ w1t) {
  int i = blockIdx.x * 256 + threadIdx.x;  // i = c*512 + k
  if (i < 512 * 128) {
    int c = i >> 9, k = i & 511;
    w1t[i] = f32_bf16(W1[k * 128 + c]);
  }
}

// ---------------- GEMM1: support1[N][128] bf16 = x @ W1 (MFMA 16x16x32) ----

__global__ __launch_bounds__(256) void k_gemm1(const float* __restrict__ x,
                                               const u16* __restrict__ w1t,
                                               u16* __restrict__ s1) {
  int wid = threadIdx.x >> 6, lane = threadIdx.x & 63;
  int tile = blockIdx.x * 4 + wid;  // 16-row tile of x
  if (tile * 16 >= N_NODES) return;
  int r0 = tile * 16;
  int m = lane & 15;
  int kg = lane >> 4;
  const float* xp = x + (size_t)(r0 + m) * 512 + kg * 8;
  const u16* wp = w1t + (size_t)m * 512 + kg * 8;

  f32x4 acc[8] = {};
#pragma unroll 2
  for (int kk = 0; kk < 512; kk += 32) {
    f32x4 a0 = *(const f32x4*)(xp + kk);
    f32x4 a1 = *(const f32x4*)(xp + kk + 4);
    short8 bfrag;
    bfrag[0] = (short)f32_bf16(a0[0]);
    bfrag[1] = (short)f32_bf16(a0[1]);
    bfrag[2] = (short)f32_bf16(a0[2]);
    bfrag[3] = (short)f32_bf16(a0[3]);
    bfrag[4] = (short)f32_bf16(a1[0]);
    bfrag[5] = (short)f32_bf16(a1[1]);
    bfrag[6] = (short)f32_bf16(a1[2]);
    bfrag[7] = (short)f32_bf16(a1[3]);
#pragma unroll
    for (int tt = 0; tt < 8; ++tt) {
      short8 afrag = *(const short8*)(wp + (size_t)tt * 16 * 512 + kk);
      acc[tt] = __builtin_amdgcn_mfma_f32_16x16x32_bf16(afrag, bfrag, acc[tt], 0, 0, 0);
    }
  }
  int row = r0 + m;
#pragma unroll
  for (int tt = 0; tt < 8; ++tt) {
    uint2 pk;
    pk.x = (u32)f32_bf16(acc[tt][0]) | ((u32)f32_bf16(acc[tt][1]) << 16);
    pk.y = (u32)f32_bf16(acc[tt][2]) | ((u32)f32_bf16(acc[tt][3]) << 16);
    *(uint2*)(s1 + (size_t)row * 128 + tt * 16 + kg * 4) = pk;
  }
}

// ---------------- layer-1 bucket aggregate + bias + relu -> h bf16 ---------
// one workgroup per 128-dst bucket; LDS fp32 accumulator [128][128].
// lane l owns u32 j=l of each s1 row (dims 2l,2l+1): lo at slot l, hi at 64+l.

__global__ __launch_bounds__(256) void k_agg1b(const uint2* __restrict__ binned,
                                               const int* __restrict__ bb,
                                               const u32* __restrict__ s1u,
                                               const float* __restrict__ b1,
                                               u32* __restrict__ h_u32) {
  __shared__ float acc[BKT_SIZE * 128];  // 64 KiB
  int t = threadIdx.x, wid = t >> 6, lane = t & 63;
  int b = blockIdx.x;
  for (int i4 = t; i4 < BKT_SIZE * 128 / 4; i4 += 256)
    ((f32x4*)acc)[i4] = f32x4{0.f, 0.f, 0.f, 0.f};
  __syncthreads();
  int beg = bb[b], end = bb[b + 1];
  int i = beg + wid * 8;
  for (; i + 8 <= end; i += 32) {
#pragma unroll
    for (int j = 0; j < 8; ++j) {
      uint2 e = binned[i + j];
      u32 src = e.x & 0xFFFFFu;
      u32 dlow = e.x >> 20;
      float w = __uint_as_float(e.y);
      u32 p = s1u[(size_t)src * 64 + lane];
      atomicAdd(&acc[dlow * 128 + lane], w * bf_lo(p));
      atomicAdd(&acc[dlow * 128 + 64 + lane], w * bf_hi(p));
    }
  }
  for (; i < end; ++i) {
    uint2 e = binned[i];
    u32 src = e.x & 0xFFFFFu;
    u32 dlow = e.x >> 20;
    float w = __uint_as_float(e.y);
    u32 p = s1u[(size_t)src * 64 + lane];
    atomicAdd(&acc[dlow * 128 + lane], w * bf_lo(p));
    atomicAdd(&acc[dlow * 128 + 64 + lane], w * bf_hi(p));
  }
  __syncthreads();
  for (int pos = t; pos < BKT_SIZE * 64; pos += 256) {
    int d = pos >> 6, j = pos & 63;
    int dstg = b * BKT_SIZE + d;
    if (dstg < N_NODES) {
      float2 bv = *(const float2*)(b1 + 2 * j);
      float lo = fmaxf(acc[d * 128 + j] + bv.x, 0.f);
      float hi = fmaxf(acc[d * 128 + 64 + j] + bv.y, 0.f);
      h_u32[(size_t)dstg * 64 + j] = (u32)f32_bf16(lo) | ((u32)f32_bf16(hi) << 16);
    }
  }
}

// ---------------- GEMM2: support2[N][40] bf16 = h @ W2 (vector fp32) -------

__global__ __launch_bounds__(320) void k_gemm2(const u16* __restrict__ h,
                                               const float* __restrict__ W2,
                                               u16* __restrict__ s2) {
  __shared__ float w2s[128 * 40];
  for (int i = threadIdx.x; i < 128 * 40; i += 320) w2s[i] = W2[i];
  __syncthreads();
  int r = blockIdx.x * 8 + threadIdx.x / 40;
  int c = threadIdx.x % 40;
  const u32* hrow = (const u32*)(h + (size_t)r * 128);
  float acc = 0.f;
#pragma unroll 8
  for (int k2 = 0; k2 < 64; ++k2) {
    u32 p = hrow[k2];
    acc += bf_lo(p) * w2s[(2 * k2) * 40 + c];
    acc += bf_hi(p) * w2s[(2 * k2 + 1) * 40 + c];
  }
  s2[(size_t)r * 40 + c] = f32_bf16(acc);
}

// ---------------- layer-2 bucket aggregate + bias + log_softmax ------------
// LDS acc [128][41] (stride 41 kills epilogue bank conflicts).
// 3 edges per wave-pass (20 lanes each), unroll x2.

__global__ __launch_bounds__(256) void k_agg2b(const uint2* __restrict__ binned,
                                               const int* __restrict__ bb,
                                               const u32* __restrict__ s2u,
                                               const float* __restrict__ b2,
                                               float* __restrict__ out) {
  __shared__ float acc[BKT_SIZE * 41];
  int t = threadIdx.x, wid = t >> 6, lane = t & 63;
  int b = blockIdx.x;
  for (int idx = t; idx < BKT_SIZE * 41; idx += 256) acc[idx] = 0.f;
  __syncthreads();
  int beg = bb[b], end = bb[b + 1];
  u32 g = (u32)lane / 20u;          // 0..3 (3 => idle)
  u32 d = (u32)lane - 20u * g;
  bool live = g < 3;
  int i = beg + wid * 6;
  for (; i + 6 <= end; i += 24) {
    uint2 E0 = binned[i],     E1 = binned[i + 1], E2 = binned[i + 2];
    uint2 E3 = binned[i + 3], E4 = binned[i + 4], E5 = binned[i + 5];
    uint2 A = (g == 1) ? E1 : ((g == 2) ? E2 : E0);
    uint2 B = (g == 1) ? E4 : ((g == 2) ? E5 : E3);
    u32 srcA = A.x & 0xFFFFFu, dA = A.x >> 20;
    u32 srcB = B.x & 0xFFFFFu, dB = B.x >> 20;
    float wA = live ? __uint_as_float(A.y) : 0.f;
    float wB = live ? __uint_as_float(B.y) : 0.f;
    u32 pA = s2u[(size_t)srcA * 20 + d];
    u32 pB = s2u[(size_t)srcB * 20 + d];
    atomicAdd(&acc[dA * 41 + 2 * d],     wA * bf_lo(pA));
    atomicAdd(&acc[dA * 41 + 2 * d + 1], wA * bf_hi(pA));
    atomicAdd(&acc[dB * 41 + 2 * d],     wB * bf_lo(pB));
    atomicAdd(&acc[dB * 41 + 2 * d + 1], wB * bf_hi(pB));
  }
  for (; i < end; ++i) {
    uint2 E0 = binned[i];
    u32 src = E0.x & 0xFFFFFu, dd = E0.x >> 20;
    float w = (g == 0) ? __uint_as_float(E0.y) : 0.f;
    u32 p = s2u[(size_t)src * 20 + d];
    atomicAdd(&acc[dd * 41 + 2 * d],     w * bf_lo(p));
    atomicAdd(&acc[dd * 41 + 2 * d + 1], w * bf_hi(p));
  }
  __syncthreads();
  if (t < BKT_SIZE) {
    int dstg = b * BKT_SIZE + t;
    if (dstg < N_NODES) {
      float v[40];
      float mx = -1e30f;
#pragma unroll
      for (int j = 0; j < 40; ++j) {
        v[j] = acc[t * 41 + j] + b2[j];
        mx = fmaxf(mx, v[j]);
      }
      float s = 0.f;
#pragma unroll
      for (int j = 0; j < 40; ++j) s += __expf(v[j] - mx);
      float ls = __logf(s);
      float* op = out + (size_t)dstg * 40;
#pragma unroll
      for (int j = 0; j < 40; ++j) op[j] = (v[j] - mx) - ls;
    }
  }
}

// ---------------- launch ----------------

extern "C" void kernel_launch(void* const* d_in, const int* in_sizes, int n_in,
                              void* d_out, int out_size, void* d_ws, size_t ws_size,
                              hipStream_t stream) {
  const float* x = (const float*)d_in[0];
  const int* ei = (const int*)d_in[1];     // int32 [2][E]
  const float* ew = (const float*)d_in[2];
  const float* W1 = (const float*)d_in[3];
  const float* b1 = (const float*)d_in[4];
  const float* W2 = (const float*)d_in[5];
  const float* b2 = (const float*)d_in[6];
  float* out = (float*)d_out;
  const int* eis = ei;             // src row
  const int* eid = ei + N_EDGES;   // dst row

  char* p = (char*)d_ws;
  u16* w1t = (u16*)p;           p += 128 * 512 * 2;                 // 128 KiB
  int* ghist = (int*)p;         p += 1024 * 4;
  int* bb = (int*)p;            p += 1024 * 4;
  int* gcur = (int*)p;          p += 1024 * 4;
  uint2* binned = (uint2*)p;    p += (size_t)N_EDGES * 8;           // 25.6 MB
  u16* s1 = (u16*)p;            p += (size_t)N_NODES * 128 * 2;     // 25.6 MB
  u16* h = (u16*)p;             p += (size_t)N_NODES * 128 * 2;     // 25.6 MB
  u16* s2 = s1;  // support1 is dead after k_agg1b; alias

  const int nchunk = (N_EDGES + CHUNK - 1) / CHUNK;  // 782
  k_w1t<<<(512 * 128) / 256, 256, 0, stream>>>(W1, w1t);
  k_zero2<<<1, 1024, 0, stream>>>(ghist);
  k_hist<<<nchunk, 256, 0, stream>>>(eid, ghist);
  k_base<<<1, 1024, 0, stream>>>(ghist, bb, gcur);
  k_bin<<<nchunk, 256, 0, stream>>>(eis, eid, ew, gcur, binned);
  k_gemm1<<<(6250 + 3) / 4, 256, 0, stream>>>(x, w1t, s1);
  k_agg1b<<<N_BKT, 256, 0, stream>>>(binned, bb, (const u32*)s1, b1, (u32*)h);
  k_gemm2<<<N_NODES / 8, 320, 0, stream>>>(h, W2, s2);
  k_agg2b<<<N_BKT, 256, 0, stream>>>(binned, bb, (const u32*)s2, b2, out);
}

// Round 5
// 744.057 us; speedup vs baseline: 5.4714x; 5.4714x over previous
//
#include <hip/hip_runtime.h>
#include <stdint.h>

#define N_NODES 100000
#define N_EDGES 3200000
#define N_BKT 782          // ceil(100000/128)
#define BKT_SHIFT 7
#define BKT_SIZE 128
#define CHUNK 4096

typedef unsigned int u32;
typedef unsigned short u16;
typedef short short8 __attribute__((ext_vector_type(8)));
typedef float f32x4 __attribute__((ext_vector_type(4)));

__device__ __forceinline__ u16 f32_bf16(float f) {
  u32 u = __float_as_uint(f);
  u += 0x7fffu + ((u >> 16) & 1u);   // RNE
  return (u16)(u >> 16);
}
__device__ __forceinline__ float bf_lo(u32 p) { return __uint_as_float(p << 16); }
__device__ __forceinline__ float bf_hi(u32 p) { return __uint_as_float(p & 0xffff0000u); }

// ---------------- bucket histogram ----------------

__global__ __launch_bounds__(1024) void k_zero2(int* ghist) {
  ghist[threadIdx.x] = 0;
}

__global__ __launch_bounds__(256) void k_hist(const int* __restrict__ eid,
                                              int* __restrict__ ghist) {
  __shared__ int hh[1024];
  int t = threadIdx.x;
  for (int b = t; b < 1024; b += 256) hh[b] = 0;
  __syncthreads();
  int base = blockIdx.x * CHUNK;
#pragma unroll
  for (int k = 0; k < 16; ++k) {
    int e = base + t + 256 * k;
    if (e < N_EDGES) atomicAdd(&hh[eid[e] >> BKT_SHIFT], 1);
  }
  __syncthreads();
  for (int b = t; b < 1024; b += 256) {
    int c = hh[b];
    if (c) atomicAdd(&ghist[b], c);
  }
}

// single-block scan of bucket counts -> bucket bases + cursors
__global__ __launch_bounds__(1024) void k_base(const int* __restrict__ ghist,
                                               int* __restrict__ bb,
                                               int* __restrict__ gcur,
                                               int* __restrict__ row_start) {
  __shared__ int sm[1024];
  int t = threadIdx.x;
  int v = (t < N_BKT) ? ghist[t] : 0;
  sm[t] = v;
  __syncthreads();
  for (int off = 1; off < 1024; off <<= 1) {
    int add = (t >= off) ? sm[t - off] : 0;
    __syncthreads();
    sm[t] += add;
    __syncthreads();
  }
  int ex = sm[t] - v;
  if (t < N_BKT) { bb[t] = ex; gcur[t] = ex; }
  if (t == 0) { bb[N_BKT] = N_EDGES; row_start[N_NODES] = N_EDGES; }
}

// ---------------- binning: block-local counting sort + coalesced flush -----
// entry pack: x = src | (dst&127)<<20 ; y = weight fp32

__global__ __launch_bounds__(256) void k_bin(const int* __restrict__ eis,
                                             const int* __restrict__ eid,
                                             const float* __restrict__ ew,
                                             int* __restrict__ gcur,
                                             uint2* __restrict__ binned) {
  __shared__ int cnt[1024];
  __shared__ int lstart[1024];
  __shared__ int delta[1024];
  __shared__ int lcur[1024];
  __shared__ int part[256];
  __shared__ uint2 stage[CHUNK];
  __shared__ u16 sbkt[CHUNK];
  int t = threadIdx.x;
  for (int b = t; b < 1024; b += 256) cnt[b] = 0;
  __syncthreads();
  int base = blockIdx.x * CHUNK;
  int cc = N_EDGES - base; if (cc > CHUNK) cc = CHUNK;
#pragma unroll
  for (int k = 0; k < 16; ++k) {
    int e = base + t + 256 * k;
    if (e < N_EDGES) atomicAdd(&cnt[eid[e] >> BKT_SHIFT], 1);
  }
  __syncthreads();
  int b4 = t * 4;
  int c0 = cnt[b4], c1 = cnt[b4 + 1], c2 = cnt[b4 + 2], c3 = cnt[b4 + 3];
  int bs = c0 + c1 + c2 + c3;
  part[t] = bs;
  __syncthreads();
  for (int off = 1; off < 256; off <<= 1) {
    int add = (t >= off) ? part[t - off] : 0;
    __syncthreads();
    part[t] += add;
    __syncthreads();
  }
  int ex = part[t] - bs;
  lstart[b4] = ex;                    lcur[b4] = ex;
  lstart[b4 + 1] = ex + c0;           lcur[b4 + 1] = ex + c0;
  lstart[b4 + 2] = ex + c0 + c1;      lcur[b4 + 2] = ex + c0 + c1;
  lstart[b4 + 3] = ex + c0 + c1 + c2; lcur[b4 + 3] = ex + c0 + c1 + c2;
  __syncthreads();
  for (int b = t; b < 1024; b += 256) {
    int c = cnt[b];
    if (c) {
      int g = atomicAdd(&gcur[b], c);
      delta[b] = g - lstart[b];
    }
  }
#pragma unroll
  for (int k = 0; k < 16; ++k) {
    int e = base + t + 256 * k;
    if (e < N_EDGES) {
      int dst = eid[e];
      int bkt = dst >> BKT_SHIFT;
      int pos = atomicAdd(&lcur[bkt], 1);
      stage[pos] = make_uint2((u32)eis[e] | ((u32)(dst & (BKT_SIZE - 1)) << 20),
                              __float_as_uint(ew[e]));
      sbkt[pos] = (u16)bkt;
    }
  }
  __syncthreads();
  for (int idx = t; idx < cc; idx += 256) {
    int bkt = sbkt[idx];
    binned[delta[bkt] + idx] = stage[idx];
  }
}

// ---------------- per-bucket exact CSR (int LDS atomics only) --------------

__global__ __launch_bounds__(256) void k_sort(const uint2* __restrict__ binned,
                                              const int* __restrict__ bb,
                                              uint2* __restrict__ entries,
                                              int* __restrict__ row_start) {
  __shared__ int cnt[BKT_SIZE];
  __shared__ int sc[BKT_SIZE];
  __shared__ int cur[BKT_SIZE];
  int t = threadIdx.x;
  int b = blockIdx.x;
  if (t < BKT_SIZE) cnt[t] = 0;
  __syncthreads();
  int beg = bb[b], end = bb[b + 1];
  for (int i = beg + t; i < end; i += 256) {
    atomicAdd(&cnt[binned[i].x >> 20], 1);
  }
  __syncthreads();
  if (t < BKT_SIZE) sc[t] = cnt[t];
  __syncthreads();
  for (int off = 1; off < BKT_SIZE; off <<= 1) {
    int add = (t < BKT_SIZE && t >= off) ? sc[t - off] : 0;
    __syncthreads();
    if (t < BKT_SIZE) sc[t] += add;
    __syncthreads();
  }
  if (t < BKT_SIZE) {
    int ex = sc[t] - cnt[t];
    cur[t] = beg + ex;
    int dstg = b * BKT_SIZE + t;
    if (dstg < N_NODES) row_start[dstg] = beg + ex;
  }
  __syncthreads();
  for (int i = beg + t; i < end; i += 256) {
    uint2 e = binned[i];
    int pos = atomicAdd(&cur[e.x >> 20], 1);
    entries[pos] = e;
  }
}

// ---------------- W1 transpose+convert: W1t[c][k] bf16 ----------------

__global__ void k_w1t(const float* __restrict__ W1, u16* __restrict__ w1t) {
  int i = blockIdx.x * 256 + threadIdx.x;  // i = c*512 + k
  if (i < 512 * 128) {
    int c = i >> 9, k = i & 511;
    w1t[i] = f32_bf16(W1[k * 128 + c]);
  }
}

// ---------------- GEMM1: support1[N][128] bf16 = x @ W1 (MFMA 16x16x32) ----

__global__ __launch_bounds__(256) void k_gemm1(const float* __restrict__ x,
                                               const u16* __restrict__ w1t,
                                               u16* __restrict__ s1) {
  int wid = threadIdx.x >> 6, lane = threadIdx.x & 63;
  int tile = blockIdx.x * 4 + wid;
  if (tile * 16 >= N_NODES) return;
  int r0 = tile * 16;
  int m = lane & 15;
  int kg = lane >> 4;
  const float* xp = x + (size_t)(r0 + m) * 512 + kg * 8;
  const u16* wp = w1t + (size_t)m * 512 + kg * 8;

  f32x4 acc[8] = {};
#pragma unroll 2
  for (int kk = 0; kk < 512; kk += 32) {
    f32x4 a0 = *(const f32x4*)(xp + kk);
    f32x4 a1 = *(const f32x4*)(xp + kk + 4);
    short8 bfrag;
    bfrag[0] = (short)f32_bf16(a0[0]);
    bfrag[1] = (short)f32_bf16(a0[1]);
    bfrag[2] = (short)f32_bf16(a0[2]);
    bfrag[3] = (short)f32_bf16(a0[3]);
    bfrag[4] = (short)f32_bf16(a1[0]);
    bfrag[5] = (short)f32_bf16(a1[1]);
    bfrag[6] = (short)f32_bf16(a1[2]);
    bfrag[7] = (short)f32_bf16(a1[3]);
#pragma unroll
    for (int tt = 0; tt < 8; ++tt) {
      short8 afrag = *(const short8*)(wp + (size_t)tt * 16 * 512 + kk);
      acc[tt] = __builtin_amdgcn_mfma_f32_16x16x32_bf16(afrag, bfrag, acc[tt], 0, 0, 0);
    }
  }
  int row = r0 + m;
#pragma unroll
  for (int tt = 0; tt < 8; ++tt) {
    uint2 pk;
    pk.x = (u32)f32_bf16(acc[tt][0]) | ((u32)f32_bf16(acc[tt][1]) << 16);
    pk.y = (u32)f32_bf16(acc[tt][2]) | ((u32)f32_bf16(acc[tt][3]) << 16);
    *(uint2*)(s1 + (size_t)row * 128 + tt * 16 + kg * 4) = pk;
  }
}

// ---------------- layer-1 aggregate + bias + relu -> h[N][128] bf16 --------
// one wave per dst; 4 edges per wave-instruction: q=lane>>4 picks edge,
// sub=lane&15 gathers uint4 (u32 idx 4sub..4sub+3 = dims 8sub..8sub+7).
// unroll x2 => 8 edges in flight. Cross-q combine: shfl_xor 16,32.

__global__ __launch_bounds__(256) void k_agg1(const uint2* __restrict__ entries,
                                              const int* __restrict__ row_start,
                                              const uint4* __restrict__ s1u4,
                                              const float* __restrict__ b1,
                                              uint4* __restrict__ h_u4) {
  int wid = threadIdx.x >> 6, lane = threadIdx.x & 63;
  int dst = blockIdx.x * 4 + wid;
  if (dst >= N_NODES) return;
  int beg = row_start[dst], end = row_start[dst + 1];
  int q = lane >> 4, sub = lane & 15;
  float a0 = 0.f, a1 = 0.f, a2 = 0.f, a3 = 0.f;
  float a4 = 0.f, a5 = 0.f, a6 = 0.f, a7 = 0.f;
  int i = beg;
  for (; i + 8 <= end; i += 8) {
    uint2 eA = entries[i + q];
    uint2 eB = entries[i + 4 + q];
    u32 sA = eA.x & 0xFFFFFu;
    u32 sB = eB.x & 0xFFFFFu;
    float wA = __uint_as_float(eA.y);
    float wB = __uint_as_float(eB.y);
    uint4 pA = s1u4[(size_t)sA * 16 + sub];
    uint4 pB = s1u4[(size_t)sB * 16 + sub];
    a0 += wA * bf_lo(pA.x); a1 += wA * bf_hi(pA.x);
    a2 += wA * bf_lo(pA.y); a3 += wA * bf_hi(pA.y);
    a4 += wA * bf_lo(pA.z); a5 += wA * bf_hi(pA.z);
    a6 += wA * bf_lo(pA.w); a7 += wA * bf_hi(pA.w);
    a0 += wB * bf_lo(pB.x); a1 += wB * bf_hi(pB.x);
    a2 += wB * bf_lo(pB.y); a3 += wB * bf_hi(pB.y);
    a4 += wB * bf_lo(pB.z); a5 += wB * bf_hi(pB.z);
    a6 += wB * bf_lo(pB.w); a7 += wB * bf_hi(pB.w);
  }
  for (; i < end; i += 4) {
    int idx = i + q;
    bool ok = idx < end;
    uint2 eA = ok ? entries[idx] : make_uint2(0u, 0u);
    u32 sA = eA.x & 0xFFFFFu;
    float wA = __uint_as_float(eA.y);
    uint4 pA = s1u4[(size_t)sA * 16 + sub];
    a0 += wA * bf_lo(pA.x); a1 += wA * bf_hi(pA.x);
    a2 += wA * bf_lo(pA.y); a3 += wA * bf_hi(pA.y);
    a4 += wA * bf_lo(pA.z); a5 += wA * bf_hi(pA.z);
    a6 += wA * bf_lo(pA.w); a7 += wA * bf_hi(pA.w);
  }
  a0 += __shfl_xor(a0, 16); a1 += __shfl_xor(a1, 16);
  a2 += __shfl_xor(a2, 16); a3 += __shfl_xor(a3, 16);
  a4 += __shfl_xor(a4, 16); a5 += __shfl_xor(a5, 16);
  a6 += __shfl_xor(a6, 16); a7 += __shfl_xor(a7, 16);
  a0 += __shfl_xor(a0, 32); a1 += __shfl_xor(a1, 32);
  a2 += __shfl_xor(a2, 32); a3 += __shfl_xor(a3, 32);
  a4 += __shfl_xor(a4, 32); a5 += __shfl_xor(a5, 32);
  a6 += __shfl_xor(a6, 32); a7 += __shfl_xor(a7, 32);
  if (q == 0) {
    f32x4 bL = *(const f32x4*)(b1 + 8 * sub);
    f32x4 bH = *(const f32x4*)(b1 + 8 * sub + 4);
    float h0 = fmaxf(a0 + bL[0], 0.f), h1 = fmaxf(a1 + bL[1], 0.f);
    float h2 = fmaxf(a2 + bL[2], 0.f), h3 = fmaxf(a3 + bL[3], 0.f);
    float h4 = fmaxf(a4 + bH[0], 0.f), h5 = fmaxf(a5 + bH[1], 0.f);
    float h6 = fmaxf(a6 + bH[2], 0.f), h7 = fmaxf(a7 + bH[3], 0.f);
    uint4 pk;
    pk.x = (u32)f32_bf16(h0) | ((u32)f32_bf16(h1) << 16);
    pk.y = (u32)f32_bf16(h2) | ((u32)f32_bf16(h3) << 16);
    pk.z = (u32)f32_bf16(h4) | ((u32)f32_bf16(h5) << 16);
    pk.w = (u32)f32_bf16(h6) | ((u32)f32_bf16(h7) << 16);
    h_u4[(size_t)dst * 16 + sub] = pk;
  }
}

// ---------------- GEMM2: support2[N][40] bf16 = h @ W2 (vector fp32) -------

__global__ __launch_bounds__(320) void k_gemm2(const u16* __restrict__ h,
                                               const float* __restrict__ W2,
                                               u16* __restrict__ s2) {
  __shared__ float w2s[128 * 40];
  for (int i = threadIdx.x; i < 128 * 40; i += 320) w2s[i] = W2[i];
  __syncthreads();
  int r = blockIdx.x * 8 + threadIdx.x / 40;
  int c = threadIdx.x % 40;
  const u32* hrow = (const u32*)(h + (size_t)r * 128);
  float acc = 0.f;
#pragma unroll 8
  for (int k2 = 0; k2 < 64; ++k2) {
    u32 p = hrow[k2];
    acc += bf_lo(p) * w2s[(2 * k2) * 40 + c];
    acc += bf_hi(p) * w2s[(2 * k2 + 1) * 40 + c];
  }
  s2[(size_t)r * 40 + c] = f32_bf16(acc);
}

// ---------------- layer-2 aggregate + bias + log_softmax -> out ------------
// one wave per dst; 3 edges per wave-instruction (20 lanes x u32), unroll x2

__global__ __launch_bounds__(256) void k_agg2(const uint2* __restrict__ entries,
                                              const int* __restrict__ row_start,
                                              const u32* __restrict__ s2u,
                                              const float* __restrict__ b2,
                                              float* __restrict__ out) {
  int wid = threadIdx.x >> 6, lane = threadIdx.x & 63;
  int dst = __builtin_amdgcn_readfirstlane(blockIdx.x * 4 + wid);
  if (dst >= N_NODES) return;
  int beg = row_start[dst], end = row_start[dst + 1];
  u32 g = (u32)lane / 20u;
  u32 d = (u32)lane - 20u * g;
  float a0 = 0.f, a1 = 0.f;
  int i = beg;
  for (; i + 6 <= end; i += 6) {
    uint2 e0 = entries[i],     e1 = entries[i + 1], e2 = entries[i + 2];
    uint2 e3 = entries[i + 3], e4 = entries[i + 4], e5 = entries[i + 5];
    uint2 A = (g == 1) ? e1 : ((g == 2) ? e2 : e0);
    uint2 B = (g == 1) ? e4 : ((g == 2) ? e5 : e3);
    u32 sA = A.x & 0xFFFFFu;
    u32 sB = B.x & 0xFFFFFu;
    float wA = __uint_as_float(A.y), wB = __uint_as_float(B.y);
    u32 pA = s2u[(size_t)sA * 20 + d];
    u32 pB = s2u[(size_t)sB * 20 + d];
    a0 += wA * bf_lo(pA); a1 += wA * bf_hi(pA);
    a0 += wB * bf_lo(pB); a1 += wB * bf_hi(pB);
  }
  for (; i < end; i += 3) {
    uint2 e0 = entries[i];
    uint2 e1 = (i + 1 < end) ? entries[i + 1] : make_uint2(e0.x, 0u);
    uint2 e2 = (i + 2 < end) ? entries[i + 2] : make_uint2(e0.x, 0u);
    uint2 A = (g == 1) ? e1 : ((g == 2) ? e2 : e0);
    u32 sA = A.x & 0xFFFFFu;
    float wA = __uint_as_float(A.y);
    u32 pA = s2u[(size_t)sA * 20 + d];
    a0 += wA * bf_lo(pA); a1 += wA * bf_hi(pA);
  }
  a0 += __shfl(a0, lane + 20) + __shfl(a0, lane + 40);
  a1 += __shfl(a1, lane + 20) + __shfl(a1, lane + 40);
  bool act = lane < 20;
  float v0 = -INFINITY, v1 = -INFINITY;
  if (act) {
    float2 bb2 = *(const float2*)(b2 + 2 * d);
    v0 = a0 + bb2.x;
    v1 = a1 + bb2.y;
  }
  float mx = fmaxf(v0, v1);
#pragma unroll
  for (int off = 16; off > 0; off >>= 1) mx = fmaxf(mx, __shfl_xor(mx, off));
  float e = act ? (__expf(v0 - mx) + __expf(v1 - mx)) : 0.f;
#pragma unroll
  for (int off = 16; off > 0; off >>= 1) e += __shfl_xor(e, off);
  if (act) {
    float ls = __logf(e);
    float2 o = make_float2((v0 - mx) - ls, (v1 - mx) - ls);
    *(float2*)(out + (size_t)dst * 40 + 2 * d) = o;
  }
}

// ---------------- launch ----------------

extern "C" void kernel_launch(void* const* d_in, const int* in_sizes, int n_in,
                              void* d_out, int out_size, void* d_ws, size_t ws_size,
                              hipStream_t stream) {
  const float* x = (const float*)d_in[0];
  const int* ei = (const int*)d_in[1];     // int32 [2][E]
  const float* ew = (const float*)d_in[2];
  const float* W1 = (const float*)d_in[3];
  const float* b1 = (const float*)d_in[4];
  const float* W2 = (const float*)d_in[5];
  const float* b2 = (const float*)d_in[6];
  float* out = (float*)d_out;
  const int* eis = ei;             // src row
  const int* eid = ei + N_EDGES;   // dst row

  char* p = (char*)d_ws;
  u16* w1t = (u16*)p;           p += 128 * 512 * 2;                 // 128 KiB
  int* ghist = (int*)p;         p += 1024 * 4;
  int* bb = (int*)p;            p += 1024 * 4;
  int* gcur = (int*)p;          p += 1024 * 4;
  int* row_start = (int*)p;     p += 100352 * 4;
  uint2* binned = (uint2*)p;    p += (size_t)N_EDGES * 8;           // 25.6 MB
  uint2* entries = (uint2*)p;   p += (size_t)N_EDGES * 8;           // 25.6 MB
  u16* s1 = (u16*)p;            p += (size_t)N_NODES * 128 * 2;     // 25.6 MB
  u16* h = (u16*)binned;  // binned dead after k_sort; alias
  u16* s2 = s1;           // s1 dead after k_agg1; alias

  const int nchunk = (N_EDGES + CHUNK - 1) / CHUNK;  // 782
  k_w1t<<<(512 * 128) / 256, 256, 0, stream>>>(W1, w1t);
  k_zero2<<<1, 1024, 0, stream>>>(ghist);
  k_hist<<<nchunk, 256, 0, stream>>>(eid, ghist);
  k_base<<<1, 1024, 0, stream>>>(ghist, bb, gcur, row_start);
  k_bin<<<nchunk, 256, 0, stream>>>(eis, eid, ew, gcur, binned);
  k_sort<<<N_BKT, 256, 0, stream>>>(binned, bb, entries, row_start);
  k_gemm1<<<(6250 + 3) / 4, 256, 0, stream>>>(x, w1t, s1);
  k_agg1<<<N_NODES / 4, 256, 0, stream>>>(entries, row_start, (const uint4*)s1, b1, (uint4*)h);
  k_gemm2<<<N_NODES / 8, 320, 0, stream>>>(h, W2, s2);
  k_agg2<<<N_NODES / 4, 256, 0, stream>>>(entries, row_start, (const u32*)s2, b2, out);
}